// Round 14
// baseline (188.792 us; speedup 1.0000x reference)
//
#include <hip/hip_runtime.h>

typedef __attribute__((ext_vector_type(8))) short bf16x8;
typedef __attribute__((ext_vector_type(8))) unsigned short u16x8;
typedef __attribute__((ext_vector_type(4))) float f32x4;
typedef __attribute__((ext_vector_type(4))) unsigned int u32x4;

constexpr int BH  = 64;    // B*H
constexpr int SEQ = 4096;  // N
constexpr int DIM = 64;    // D
constexpr int PM  = 256;   // M (proj_len)
constexpr size_t PLANE = (size_t)BH * PM * DIM;   // 1,048,576 elements

__device__ __forceinline__ unsigned short f2bf(float f){
    unsigned int u = __float_as_uint(f);
    return (unsigned short)((u + 0x7fffu + ((u >> 16) & 1u)) >> 16);
}
__device__ __forceinline__ float bf2f(unsigned short h){
    return __uint_as_float(((unsigned int)h) << 16);
}
__device__ __forceinline__ unsigned short f2h(float f){
    _Float16 h = (_Float16)f;
    unsigned short u;
    __builtin_memcpy(&u, &h, 2);
    return u;
}
__device__ __forceinline__ float h2f(unsigned short u){
    _Float16 h;
    __builtin_memcpy(&h, &u, 2);
    return (float)h;
}

// ---------------- kernel 1: E [N][M] f32 -> Et_hi/Et_lo [M][N] bf16 (split) ----------------
__global__ __launch_bounds__(256) void prep_e_kernel(const float* __restrict__ E,
                                                     unsigned short* __restrict__ Et_hi,
                                                     unsigned short* __restrict__ Et_lo){
    __shared__ float T[64][65];
    int n0 = (blockIdx.x & 63) * 64;
    int m0 = (blockIdx.x >> 6) * 64;
    int t = threadIdx.x;
    #pragma unroll
    for (int i = 0; i < 16; ++i){
        int idx = t + i * 256;
        int nl = idx >> 6, ml = idx & 63;
        T[nl][ml] = E[(size_t)(n0 + nl) * PM + (m0 + ml)];
    }
    __syncthreads();
    #pragma unroll
    for (int i = 0; i < 16; ++i){
        int idx = t + i * 256;
        int ml = idx >> 6, nl = idx & 63;
        float v = T[nl][ml];
        unsigned short h = f2bf(v);
        unsigned short lo = f2bf(v - bf2f(h));
        size_t o = (size_t)(m0 + ml) * SEQ + (n0 + nl);
        Et_hi[o] = h;
        Et_lo[o] = lo;
    }
}

// ---------------- kernel 2: projection partials — R12 structure + pass-0 K/V prefetch ----
// grid 1024 = 8 s x (64 bh x 2 mh); 256 threads; 4 blocks/CU (16 waves/CU).
// AGPR budget note: acc = 64 regs (AGPR half of unified file); VGPR half = 64.
// R12 placement (Et loads AFTER barrier) keeps peak VGPR <= 64. New: pass-0
// K/V rows for iter n+1 prefetched into 16 regs during the MFMA phase — loads
// can't cross __syncthreads, so they overlap Et-loads+MFMA and kill the
// ~900cy cold-start stall at each iter head. MFMA-phase VGPRs: 32(ehl)+16(pf)
// +addr ~= 58 <= 64 (R13's spill was 32+16+16 staging overlap).
__global__ __launch_bounds__(256, 4) void proj_partial_kernel(const float* __restrict__ K,
                                                              const float* __restrict__ V,
                                                              const unsigned short* __restrict__ Et_hi,
                                                              const unsigned short* __restrict__ Et_lo,
                                                              float* __restrict__ PK,
                                                              unsigned short* __restrict__ PV){
    __shared__ unsigned short Kh[64][72], Kl[64][72], Vh[64][72];
    int bid   = blockIdx.x;
    int s     = bid & 7;
    int rest  = bid >> 3;          // 0..127
    int mh    = rest & 1;          // m-half: pair-adjacent in dispatch order
    int bh    = rest >> 1;
    int nbase = s * (SEQ / 8);
    int nend  = nbase + SEQ / 8;
    int t = threadIdx.x;
    int w = t >> 6, l = t & 63, l15 = l & 15, lg = l >> 4;
    int m0w = mh * 128 + w * 32;   // wave's 32-row m-chunk

    const float* Kb = K + (size_t)bh * SEQ * DIM;
    const float* Vb = V + (size_t)bh * SEQ * DIM;
    int d  = t & 63;
    int ng = t >> 6;               // 0..3

    f32x4 accK[2][4], accV[4][2];  // [ms][dt] / [dt][ms]
    #pragma unroll
    for (int i = 0; i < 2; ++i)
        #pragma unroll
        for (int j = 0; j < 4; ++j){ accK[i][j] = (f32x4)0.0f; accV[j][i] = (f32x4)0.0f; }

    // prologue: prefetch pass-0 rows (nb = ng*8) of the first iter
    float pkf[8], pvf[8];
    #pragma unroll
    for (int i = 0; i < 8; ++i){
        pkf[i] = Kb[(size_t)(nbase + ng * 8 + i) * DIM + d];
        pvf[i] = Vb[(size_t)(nbase + ng * 8 + i) * DIM + d];
    }

    for (int n0 = nbase; n0 < nend; n0 += 64){
        // pass 0: convert prefetched rows, store to LDS
        {
            int nb = ng * 8;
            u16x8 kh, kl, vh;
            #pragma unroll
            for (int i = 0; i < 8; ++i){
                unsigned short h = f2bf(pkf[i]);
                kh[i] = h;
                kl[i] = f2bf(pkf[i] - bf2f(h));
                vh[i] = f2bf(pvf[i]);
            }
            *reinterpret_cast<u16x8*>(&Kh[d][nb]) = kh;
            *reinterpret_cast<u16x8*>(&Kl[d][nb]) = kl;
            *reinterpret_cast<u16x8*>(&Vh[d][nb]) = vh;
        }
        // pass 1: load + convert + store rows nb = 32 + ng*8
        {
            int nb = 32 + ng * 8;
            float kf[8], vf[8];
            #pragma unroll
            for (int i = 0; i < 8; ++i){
                kf[i] = Kb[(size_t)(n0 + nb + i) * DIM + d];
                vf[i] = Vb[(size_t)(n0 + nb + i) * DIM + d];
            }
            u16x8 kh, kl, vh;
            #pragma unroll
            for (int i = 0; i < 8; ++i){
                unsigned short h = f2bf(kf[i]);
                kh[i] = h;
                kl[i] = f2bf(kf[i] - bf2f(h));
                vh[i] = f2bf(vf[i]);
            }
            *reinterpret_cast<u16x8*>(&Kh[d][nb]) = kh;
            *reinterpret_cast<u16x8*>(&Kl[d][nb]) = kl;
            *reinterpret_cast<u16x8*>(&Vh[d][nb]) = vh;
        }
        __syncthreads();
        // Et fragments (L2-resident; loaded here so staging VGPRs are dead — R12 placement)
        bf16x8 eh[2][2], el[2][2];
        #pragma unroll
        for (int nk = 0; nk < 2; ++nk){
            #pragma unroll
            for (int ms = 0; ms < 2; ++ms){
                size_t off = (size_t)(m0w + ms * 16 + l15) * SEQ + (n0 + nk * 32 + lg * 8);
                eh[nk][ms] = *reinterpret_cast<const bf16x8*>(Et_hi + off);
                el[nk][ms] = *reinterpret_cast<const bf16x8*>(Et_lo + off);
            }
        }
        // prefetch next iter's pass-0 rows (overlaps Et loads + MFMA below)
        if (n0 + 64 < nend){
            #pragma unroll
            for (int i = 0; i < 8; ++i){
                pkf[i] = Kb[(size_t)(n0 + 64 + ng * 8 + i) * DIM + d];
                pvf[i] = Vb[(size_t)(n0 + 64 + ng * 8 + i) * DIM + d];
            }
        }
        #pragma unroll
        for (int nk = 0; nk < 2; ++nk){
            int kb = nk * 32 + lg * 8;
            #pragma unroll
            for (int dt = 0; dt < 4; ++dt){
                bf16x8 kh = *reinterpret_cast<const bf16x8*>(&Kh[dt * 16 + l15][kb]);
                bf16x8 kl = *reinterpret_cast<const bf16x8*>(&Kl[dt * 16 + l15][kb]);
                bf16x8 vh = *reinterpret_cast<const bf16x8*>(&Vh[dt * 16 + l15][kb]);
                #pragma unroll
                for (int ms = 0; ms < 2; ++ms){
                    accK[ms][dt] = __builtin_amdgcn_mfma_f32_16x16x32_bf16(eh[nk][ms], kh, accK[ms][dt], 0, 0, 0);
                    accK[ms][dt] = __builtin_amdgcn_mfma_f32_16x16x32_bf16(eh[nk][ms], kl, accK[ms][dt], 0, 0, 0);
                    accK[ms][dt] = __builtin_amdgcn_mfma_f32_16x16x32_bf16(el[nk][ms], kh, accK[ms][dt], 0, 0, 0);
                    accV[dt][ms] = __builtin_amdgcn_mfma_f32_16x16x32_bf16(vh, eh[nk][ms], accV[dt][ms], 0, 0, 0);
                }
            }
        }
        __syncthreads();
    }

    float*          PKb = PK + ((size_t)s * BH + bh) * PM * DIM;
    unsigned short* PVb = PV + ((size_t)s * BH + bh) * DIM * PM;
    #pragma unroll
    for (int ms = 0; ms < 2; ++ms){
        #pragma unroll
        for (int dt = 0; dt < 4; ++dt){
            #pragma unroll
            for (int j = 0; j < 4; ++j){
                int mg = m0w + ms * 16 + lg * 4 + j;
                int dg = dt * 16 + l15;
                PKb[(size_t)mg * DIM + dg] = accK[ms][dt][j];
                int dr = dt * 16 + lg * 4 + j;
                int mc = m0w + ms * 16 + l15;
                PVb[(size_t)dr * PM + mc] = f2h(accV[dt][ms][j]);
            }
        }
    }
}

// ---------------- kernel 2b: reduce 8 partials (K f32, V f16) -> Kp_hi/Kp_lo/Vpt ----------------
__global__ __launch_bounds__(256) void reduce_kernel(const float* __restrict__ PK,
                                                     const unsigned short* __restrict__ PV,
                                                     unsigned short* __restrict__ Kp_hi,
                                                     unsigned short* __restrict__ Kp_lo,
                                                     unsigned short* __restrict__ Vpt){
    size_t e8 = (size_t)blockIdx.x * 256 + threadIdx.x;   // 8 elements per thread
    const u16x8* PV8 = reinterpret_cast<const u16x8*>(PV);
    size_t stride8 = PLANE / 8;

    float k[8], v[8];
    {
        float4 a = *reinterpret_cast<const float4*>(PK + e8 * 8);
        float4 b = *reinterpret_cast<const float4*>(PK + e8 * 8 + 4);
        k[0]=a.x; k[1]=a.y; k[2]=a.z; k[3]=a.w; k[4]=b.x; k[5]=b.y; k[6]=b.z; k[7]=b.w;
        u16x8 c = PV8[e8];
        #pragma unroll
        for (int i = 0; i < 8; ++i) v[i] = h2f(c[i]);
    }
    #pragma unroll
    for (int s = 1; s < 8; ++s){
        float4 a = *reinterpret_cast<const float4*>(PK + (size_t)s * PLANE + e8 * 8);
        float4 b = *reinterpret_cast<const float4*>(PK + (size_t)s * PLANE + e8 * 8 + 4);
        k[0]+=a.x; k[1]+=a.y; k[2]+=a.z; k[3]+=a.w; k[4]+=b.x; k[5]+=b.y; k[6]+=b.z; k[7]+=b.w;
        u16x8 c = PV8[e8 + (size_t)s * stride8];
        #pragma unroll
        for (int i = 0; i < 8; ++i) v[i] += h2f(c[i]);
    }
    u16x8 hi, lo, vb;
    #pragma unroll
    for (int i = 0; i < 8; ++i){
        unsigned short h = f2bf(k[i]);
        hi[i] = h;
        lo[i] = f2bf(k[i] - bf2f(h));
        vb[i] = f2bf(v[i]);
    }
    *reinterpret_cast<u16x8*>(Kp_hi + e8 * 8) = hi;
    *reinterpret_cast<u16x8*>(Kp_lo + e8 * 8) = lo;
    *reinterpret_cast<u16x8*>(Vpt   + e8 * 8) = vb;
}

// ---------------- kernel 3: attention — 512 threads, register-P (R12, proven) ----------------
constexpr int ATTN_LDS_BYTES = (2 * 128 * 72 + 64 * 136) * 2;  // 54,272

__global__ __launch_bounds__(512, 4) void attn_kernel(const float* __restrict__ Q,
                                                      const unsigned short* __restrict__ Kp_hi,
                                                      const unsigned short* __restrict__ Kp_lo,
                                                      const unsigned short* __restrict__ Vpt,
                                                      float* __restrict__ Out){
    extern __shared__ unsigned short smem[];
    unsigned short (*Kh)[72]  = reinterpret_cast<unsigned short (*)[72]>(smem);                 // [128][72]
    unsigned short (*Kl)[72]  = reinterpret_cast<unsigned short (*)[72]>(smem + 128 * 72);      // [128][72]
    unsigned short (*Vt)[136] = reinterpret_cast<unsigned short (*)[136]>(smem + 2 * 128 * 72); // [64][136]

    int bid  = blockIdx.x;
    int orig = (bid & 7) * 128 + (bid >> 3);  // XCD-chunked: 8 heads per XCD
    int bh   = orig >> 4;
    int q0   = (orig & 15) * 256;
    int t = threadIdx.x;              // 0..511
    int w = t >> 6, l = t & 63, l15 = l & 15, lg = l >> 4;

    const float* Qw = Q   + ((size_t)bh * SEQ + q0 + w * 32) * DIM;
    float*       Ow = Out + ((size_t)bh * SEQ + q0 + w * 32) * DIM;

    bf16x8 qh[2][2], ql[2][2];
    #pragma unroll
    for (int rt = 0; rt < 2; ++rt){
        const float* Qb = Qw + (size_t)(rt * 16 + l15) * DIM;
        #pragma unroll
        for (int nk = 0; nk < 2; ++nk){
            float4 a = *reinterpret_cast<const float4*>(Qb + nk * 32 + lg * 8);
            float4 b = *reinterpret_cast<const float4*>(Qb + nk * 32 + lg * 8 + 4);
            float vals[8] = {a.x, a.y, a.z, a.w, b.x, b.y, b.z, b.w};
            #pragma unroll
            for (int i = 0; i < 8; ++i){
                float v = vals[i] * 0.125f;   // fold 1/sqrt(D)
                unsigned short h = f2bf(v);
                qh[rt][nk][i] = (short)h;
                ql[rt][nk][i] = (short)f2bf(v - bf2f(h));
            }
        }
    }

    const unsigned short* KHb = Kp_hi + (size_t)bh * PM * DIM;
    const unsigned short* KLb = Kp_lo + (size_t)bh * PM * DIM;
    const unsigned short* VTb = Vpt   + (size_t)bh * DIM * PM;

    float mx[2], sm[2];
    f32x4 oacc[2][4];   // [rt][dt]
    #pragma unroll
    for (int rt = 0; rt < 2; ++rt){
        mx[rt] = -3.0e38f; sm[rt] = 0.0f;
        #pragma unroll
        for (int dt = 0; dt < 4; ++dt) oacc[rt][dt] = (f32x4)0.0f;
    }

    int srcA = l15 + (lg & 1) * 32;   // P-shuffle source lanes
    int srcB = srcA + 16;
    bool hi2 = (lg & 2) != 0;

    for (int h = 0; h < 2; ++h){
        if (h) __syncthreads();   // all waves done with previous half
        #pragma unroll
        for (int i = 0; i < 2; ++i){
            int idx = i * 512 + t;
            int r = idx >> 3, c = (idx & 7) * 8;
            *reinterpret_cast<u16x8*>(&Kh[r][c]) = *reinterpret_cast<const u16x8*>(KHb + (size_t)(h * 128 + r) * DIM + c);
            *reinterpret_cast<u16x8*>(&Kl[r][c]) = *reinterpret_cast<const u16x8*>(KLb + (size_t)(h * 128 + r) * DIM + c);
        }
        #pragma unroll
        for (int i = 0; i < 2; ++i){
            int idx = i * 512 + t;
            int r = idx >> 4, c = (idx & 15) * 8;
            *reinterpret_cast<u16x8*>(&Vt[r][c]) = *reinterpret_cast<const u16x8*>(VTb + (size_t)r * PM + h * 128 + c);
        }
        __syncthreads();

#define RT_BODY(RT, QT)                                                              \
        {                                                                            \
            f32x4 sa[4];                                                             \
            _Pragma("unroll")                                                        \
            for (int i = 0; i < 4; ++i) sa[i] = (f32x4)0.0f;                         \
            _Pragma("unroll")                                                        \
            for (int mi = 0; mi < 4; ++mi){                                          \
                _Pragma("unroll")                                                    \
                for (int nk = 0; nk < 2; ++nk){                                      \
                    bf16x8 kh_ = *reinterpret_cast<const bf16x8*>(&Kh[QT * 64 + mi * 16 + l15][nk * 32 + lg * 8]); \
                    bf16x8 kl_ = *reinterpret_cast<const bf16x8*>(&Kl[QT * 64 + mi * 16 + l15][nk * 32 + lg * 8]); \
                    sa[mi] = __builtin_amdgcn_mfma_f32_16x16x32_bf16(kh_, qh[RT][nk], sa[mi], 0, 0, 0);  \
                    sa[mi] = __builtin_amdgcn_mfma_f32_16x16x32_bf16(kl_, qh[RT][nk], sa[mi], 0, 0, 0);  \
                    sa[mi] = __builtin_amdgcn_mfma_f32_16x16x32_bf16(kh_, ql[RT][nk], sa[mi], 0, 0, 0);  \
                }                                                                    \
            }                                                                        \
            float hm = -3.0e38f;                                                     \
            _Pragma("unroll")                                                        \
            for (int mi = 0; mi < 4; ++mi)                                           \
                _Pragma("unroll")                                                    \
                for (int j = 0; j < 4; ++j) hm = fmaxf(hm, sa[mi][j]);               \
            hm = fmaxf(hm, __shfl_xor(hm, 16, 64));                                  \
            hm = fmaxf(hm, __shfl_xor(hm, 32, 64));                                  \
            bool keep = __all(hm <= mx[RT] + 8.0f);                                  \
            float nm = keep ? mx[RT] : fmaxf(mx[RT], hm);                            \
            float ps = 0.0f;                                                         \
            _Pragma("unroll")                                                        \
            for (int mi = 0; mi < 4; ++mi)                                           \
                _Pragma("unroll")                                                    \
                for (int j = 0; j < 4; ++j){                                         \
                    float p = __expf(sa[mi][j] - nm);                                \
                    sa[mi][j] = p;                                                   \
                    ps += p;                                                         \
                }                                                                    \
            ps += __shfl_xor(ps, 16, 64);                                            \
            ps += __shfl_xor(ps, 32, 64);                                            \
            if (keep){                                                               \
                sm[RT] += ps;                                                        \
            } else {                                                                 \
                float sc = __expf(mx[RT] - nm);                                      \
                mx[RT] = nm;                                                         \
                sm[RT] = sm[RT] * sc + ps;                                           \
                float scj[4];                                                        \
                _Pragma("unroll")                                                    \
                for (int j = 0; j < 4; ++j) scj[j] = __shfl(sc, lg * 20 + j, 64);    \
                _Pragma("unroll")                                                    \
                for (int dt = 0; dt < 4; ++dt)                                       \
                    _Pragma("unroll")                                                \
                    for (int j = 0; j < 4; ++j) oacc[RT][dt][j] *= scj[j];           \
            }                                                                        \
            int pka[4], pkb[4];                                                      \
            _Pragma("unroll")                                                        \
            for (int mi = 0; mi < 4; ++mi){                                          \
                pka[mi] = (int)(((unsigned)f2bf(sa[mi][0])) | (((unsigned)f2bf(sa[mi][1])) << 16)); \
                pkb[mi] = (int)(((unsigned)f2bf(sa[mi][2])) | (((unsigned)f2bf(sa[mi][3])) << 16)); \
            }                                                                        \
            _Pragma("unroll")                                                        \
            for (int mk = 0; mk < 2; ++mk){                                          \
                int a0 = __shfl(pka[2 * mk],     srcA, 64);                          \
                int a1 = __shfl(pka[2 * mk + 1], srcA, 64);                          \
                int b0 = __shfl(pkb[2 * mk],     srcA, 64);                          \
                int b1 = __shfl(pkb[2 * mk + 1], srcA, 64);                          \
                int c0 = __shfl(pka[2 * mk],     srcB, 64);                          \
                int c1 = __shfl(pka[2 * mk + 1], srcB, 64);                          \
                int e0 = __shfl(pkb[2 * mk],     srcB, 64);                          \
                int e1 = __shfl(pkb[2 * mk + 1], srcB, 64);                          \
                u32x4 pd;                                                            \
                pd.x = (unsigned)(hi2 ? a1 : a0);                                    \
                pd.y = (unsigned)(hi2 ? b1 : b0);                                    \
                pd.z = (unsigned)(hi2 ? c1 : c0);                                    \
                pd.w = (unsigned)(hi2 ? e1 : e0);                                    \
                bf16x8 pa = __builtin_bit_cast(bf16x8, pd);                          \
                _Pragma("unroll")                                                    \
                for (int dt = 0; dt < 4; ++dt){                                      \
                    bf16x8 bv = *reinterpret_cast<const bf16x8*>(&Vt[dt * 16 + l15][QT * 64 + mk * 32 + lg * 8]); \
                    oacc[RT][dt] = __builtin_amdgcn_mfma_f32_16x16x32_bf16(pa, bv, oacc[RT][dt], 0, 0, 0); \
                }                                                                    \
            }                                                                        \
        }

        RT_BODY(0, 0)
        RT_BODY(1, 0)
        RT_BODY(0, 1)
        RT_BODY(1, 1)
#undef RT_BODY
    }

    #pragma unroll
    for (int rt = 0; rt < 2; ++rt){
        float inv = 1.0f / sm[rt];
        float invj[4];
        #pragma unroll
        for (int j = 0; j < 4; ++j) invj[j] = __shfl(inv, lg * 20 + j, 64);
        #pragma unroll
        for (int dt = 0; dt < 4; ++dt)
            #pragma unroll
            for (int j = 0; j < 4; ++j)
                Ow[(size_t)(rt * 16 + lg * 4 + j) * DIM + dt * 16 + l15] = oacc[rt][dt][j] * invj[j];
    }
}

extern "C" void kernel_launch(void* const* d_in, const int* in_sizes, int n_in,
                              void* d_out, int out_size, void* d_ws, size_t ws_size,
                              hipStream_t stream){
    const float* Q = (const float*)d_in[0];
    const float* K = (const float*)d_in[1];
    const float* V = (const float*)d_in[2];
    const float* E = (const float*)d_in[3];
    float* out = (float*)d_out;

    unsigned short* Et_hi = (unsigned short*)d_ws;                       // [M][N]
    unsigned short* Et_lo = Et_hi + (size_t)PM * SEQ;                    // [M][N]
    unsigned short* Kp_hi = Et_lo + (size_t)PM * SEQ;                    // [BH][M][D]
    unsigned short* Kp_lo = Kp_hi + PLANE;                               // [BH][M][D]
    unsigned short* Vpt   = Kp_lo + PLANE;                               // [BH][D][M]
    size_t base_bytes = ((size_t)PM * SEQ * 2 + PLANE * 3) * sizeof(unsigned short);
    float* PK          = reinterpret_cast<float*>((char*)d_ws + base_bytes);  // [8][BH][M][D] f32
    unsigned short* PV = reinterpret_cast<unsigned short*>(PK + 8 * PLANE);   // [8][BH][D][M] f16

    prep_e_kernel<<<256, 256, 0, stream>>>(E, Et_hi, Et_lo);
    proj_partial_kernel<<<1024, 256, 0, stream>>>(K, V, Et_hi, Et_lo, PK, PV);
    reduce_kernel<<<PLANE / 8 / 256, 256, 0, stream>>>(PK, PV, Kp_hi, Kp_lo, Vpt);
    attn_kernel<<<1024, 512, ATTN_LDS_BYTES, stream>>>(Q, Kp_hi, Kp_lo, Vpt, out);
}

// Round 15
// 163.112 us; speedup vs baseline: 1.1574x; 1.1574x over previous
//
#include <hip/hip_runtime.h>

typedef __attribute__((ext_vector_type(8))) short bf16x8;
typedef __attribute__((ext_vector_type(8))) unsigned short u16x8;
typedef __attribute__((ext_vector_type(4))) float f32x4;
typedef __attribute__((ext_vector_type(4))) unsigned int u32x4;

constexpr int BH  = 64;    // B*H
constexpr int SEQ = 4096;  // N
constexpr int DIM = 64;    // D
constexpr int PM  = 256;   // M (proj_len)
constexpr size_t PLANE = (size_t)BH * PM * DIM;   // 1,048,576 elements

__device__ __forceinline__ unsigned short f2bf(float f){
    unsigned int u = __float_as_uint(f);
    return (unsigned short)((u + 0x7fffu + ((u >> 16) & 1u)) >> 16);
}
__device__ __forceinline__ float bf2f(unsigned short h){
    return __uint_as_float(((unsigned int)h) << 16);
}
__device__ __forceinline__ unsigned short f2h(float f){
    _Float16 h = (_Float16)f;
    unsigned short u;
    __builtin_memcpy(&u, &h, 2);
    return u;
}
__device__ __forceinline__ float h2f(unsigned short u){
    _Float16 h;
    __builtin_memcpy(&h, &u, 2);
    return (float)h;
}

// ---------------- kernel 1: E [N][M] f32 -> Et_hi/Et_lo [M][N] bf16 (split) ----------------
__global__ __launch_bounds__(256) void prep_e_kernel(const float* __restrict__ E,
                                                     unsigned short* __restrict__ Et_hi,
                                                     unsigned short* __restrict__ Et_lo){
    __shared__ float T[64][65];
    int n0 = (blockIdx.x & 63) * 64;
    int m0 = (blockIdx.x >> 6) * 64;
    int t = threadIdx.x;
    #pragma unroll
    for (int i = 0; i < 16; ++i){
        int idx = t + i * 256;
        int nl = idx >> 6, ml = idx & 63;
        T[nl][ml] = E[(size_t)(n0 + nl) * PM + (m0 + ml)];
    }
    __syncthreads();
    #pragma unroll
    for (int i = 0; i < 16; ++i){
        int idx = t + i * 256;
        int ml = idx >> 6, nl = idx & 63;
        float v = T[nl][ml];
        unsigned short h = f2bf(v);
        unsigned short lo = f2bf(v - bf2f(h));
        size_t o = (size_t)(m0 + ml) * SEQ + (n0 + nl);
        Et_hi[o] = h;
        Et_lo[o] = lo;
    }
}

// ---------------- kernel 2: projection partials — R12 structure + pass-0 prefetch at 3 waves/SIMD ----
// grid 1024 = 8 s x (64 bh x 2 mh); 256 threads. R13/R14 spilled because the
// (256,4) cap leaves only 64 VGPRs beside the 64 AGPR acc — R12 fills that
// exactly. (256,3) raises the budget to ~170: acc 64 AGPR + ~90 VGPR fits with
// headroom, so the pass-0 K/V prefetch (16 regs, issued in the MFMA phase to
// hide the ~900cy iter-head cold load) cannot spill. Trade: 16 -> 12 waves/CU.
// Decision rule: WRITE_SIZE > 70 MB or proj > 80 us => revert to R12-proj.
__global__ __launch_bounds__(256, 3) void proj_partial_kernel(const float* __restrict__ K,
                                                              const float* __restrict__ V,
                                                              const unsigned short* __restrict__ Et_hi,
                                                              const unsigned short* __restrict__ Et_lo,
                                                              float* __restrict__ PK,
                                                              unsigned short* __restrict__ PV){
    __shared__ unsigned short Kh[64][72], Kl[64][72], Vh[64][72];
    int bid   = blockIdx.x;
    int s     = bid & 7;
    int rest  = bid >> 3;          // 0..127
    int mh    = rest & 1;          // m-half: pair-adjacent in dispatch order
    int bh    = rest >> 1;
    int nbase = s * (SEQ / 8);
    int nend  = nbase + SEQ / 8;
    int t = threadIdx.x;
    int w = t >> 6, l = t & 63, l15 = l & 15, lg = l >> 4;
    int m0w = mh * 128 + w * 32;   // wave's 32-row m-chunk

    const float* Kb = K + (size_t)bh * SEQ * DIM;
    const float* Vb = V + (size_t)bh * SEQ * DIM;
    int d  = t & 63;
    int ng = t >> 6;               // 0..3

    f32x4 accK[2][4], accV[4][2];  // [ms][dt] / [dt][ms]
    #pragma unroll
    for (int i = 0; i < 2; ++i)
        #pragma unroll
        for (int j = 0; j < 4; ++j){ accK[i][j] = (f32x4)0.0f; accV[j][i] = (f32x4)0.0f; }

    // prologue: prefetch pass-0 rows (nb = ng*8) of the first iter
    float pkf[8], pvf[8];
    #pragma unroll
    for (int i = 0; i < 8; ++i){
        pkf[i] = Kb[(size_t)(nbase + ng * 8 + i) * DIM + d];
        pvf[i] = Vb[(size_t)(nbase + ng * 8 + i) * DIM + d];
    }

    for (int n0 = nbase; n0 < nend; n0 += 64){
        // pass 0: convert prefetched rows, store to LDS
        {
            int nb = ng * 8;
            u16x8 kh, kl, vh;
            #pragma unroll
            for (int i = 0; i < 8; ++i){
                unsigned short h = f2bf(pkf[i]);
                kh[i] = h;
                kl[i] = f2bf(pkf[i] - bf2f(h));
                vh[i] = f2bf(pvf[i]);
            }
            *reinterpret_cast<u16x8*>(&Kh[d][nb]) = kh;
            *reinterpret_cast<u16x8*>(&Kl[d][nb]) = kl;
            *reinterpret_cast<u16x8*>(&Vh[d][nb]) = vh;
        }
        // pass 1: load + convert + store rows nb = 32 + ng*8
        {
            int nb = 32 + ng * 8;
            float kf[8], vf[8];
            #pragma unroll
            for (int i = 0; i < 8; ++i){
                kf[i] = Kb[(size_t)(n0 + nb + i) * DIM + d];
                vf[i] = Vb[(size_t)(n0 + nb + i) * DIM + d];
            }
            u16x8 kh, kl, vh;
            #pragma unroll
            for (int i = 0; i < 8; ++i){
                unsigned short h = f2bf(kf[i]);
                kh[i] = h;
                kl[i] = f2bf(kf[i] - bf2f(h));
                vh[i] = f2bf(vf[i]);
            }
            *reinterpret_cast<u16x8*>(&Kh[d][nb]) = kh;
            *reinterpret_cast<u16x8*>(&Kl[d][nb]) = kl;
            *reinterpret_cast<u16x8*>(&Vh[d][nb]) = vh;
        }
        __syncthreads();
        // Et fragments (L2-resident; loaded after barrier — R12 placement)
        bf16x8 eh[2][2], el[2][2];
        #pragma unroll
        for (int nk = 0; nk < 2; ++nk){
            #pragma unroll
            for (int ms = 0; ms < 2; ++ms){
                size_t off = (size_t)(m0w + ms * 16 + l15) * SEQ + (n0 + nk * 32 + lg * 8);
                eh[nk][ms] = *reinterpret_cast<const bf16x8*>(Et_hi + off);
                el[nk][ms] = *reinterpret_cast<const bf16x8*>(Et_lo + off);
            }
        }
        // prefetch next iter's pass-0 rows (overlaps Et loads + MFMA below)
        if (n0 + 64 < nend){
            #pragma unroll
            for (int i = 0; i < 8; ++i){
                pkf[i] = Kb[(size_t)(n0 + 64 + ng * 8 + i) * DIM + d];
                pvf[i] = Vb[(size_t)(n0 + 64 + ng * 8 + i) * DIM + d];
            }
        }
        #pragma unroll
        for (int nk = 0; nk < 2; ++nk){
            int kb = nk * 32 + lg * 8;
            #pragma unroll
            for (int dt = 0; dt < 4; ++dt){
                bf16x8 kh = *reinterpret_cast<const bf16x8*>(&Kh[dt * 16 + l15][kb]);
                bf16x8 kl = *reinterpret_cast<const bf16x8*>(&Kl[dt * 16 + l15][kb]);
                bf16x8 vh = *reinterpret_cast<const bf16x8*>(&Vh[dt * 16 + l15][kb]);
                #pragma unroll
                for (int ms = 0; ms < 2; ++ms){
                    accK[ms][dt] = __builtin_amdgcn_mfma_f32_16x16x32_bf16(eh[nk][ms], kh, accK[ms][dt], 0, 0, 0);
                    accK[ms][dt] = __builtin_amdgcn_mfma_f32_16x16x32_bf16(eh[nk][ms], kl, accK[ms][dt], 0, 0, 0);
                    accK[ms][dt] = __builtin_amdgcn_mfma_f32_16x16x32_bf16(el[nk][ms], kh, accK[ms][dt], 0, 0, 0);
                    accV[dt][ms] = __builtin_amdgcn_mfma_f32_16x16x32_bf16(vh, eh[nk][ms], accV[dt][ms], 0, 0, 0);
                }
            }
        }
        __syncthreads();
    }

    float*          PKb = PK + ((size_t)s * BH + bh) * PM * DIM;
    unsigned short* PVb = PV + ((size_t)s * BH + bh) * DIM * PM;
    #pragma unroll
    for (int ms = 0; ms < 2; ++ms){
        #pragma unroll
        for (int dt = 0; dt < 4; ++dt){
            #pragma unroll
            for (int j = 0; j < 4; ++j){
                int mg = m0w + ms * 16 + lg * 4 + j;
                int dg = dt * 16 + l15;
                PKb[(size_t)mg * DIM + dg] = accK[ms][dt][j];
                int dr = dt * 16 + lg * 4 + j;
                int mc = m0w + ms * 16 + l15;
                PVb[(size_t)dr * PM + mc] = f2h(accV[dt][ms][j]);
            }
        }
    }
}

// ---------------- kernel 2b: reduce 8 partials (K f32, V f16) -> Kp_hi/Kp_lo/Vpt ----------------
__global__ __launch_bounds__(256) void reduce_kernel(const float* __restrict__ PK,
                                                     const unsigned short* __restrict__ PV,
                                                     unsigned short* __restrict__ Kp_hi,
                                                     unsigned short* __restrict__ Kp_lo,
                                                     unsigned short* __restrict__ Vpt){
    size_t e8 = (size_t)blockIdx.x * 256 + threadIdx.x;   // 8 elements per thread
    const u16x8* PV8 = reinterpret_cast<const u16x8*>(PV);
    size_t stride8 = PLANE / 8;

    float k[8], v[8];
    {
        float4 a = *reinterpret_cast<const float4*>(PK + e8 * 8);
        float4 b = *reinterpret_cast<const float4*>(PK + e8 * 8 + 4);
        k[0]=a.x; k[1]=a.y; k[2]=a.z; k[3]=a.w; k[4]=b.x; k[5]=b.y; k[6]=b.z; k[7]=b.w;
        u16x8 c = PV8[e8];
        #pragma unroll
        for (int i = 0; i < 8; ++i) v[i] = h2f(c[i]);
    }
    #pragma unroll
    for (int s = 1; s < 8; ++s){
        float4 a = *reinterpret_cast<const float4*>(PK + (size_t)s * PLANE + e8 * 8);
        float4 b = *reinterpret_cast<const float4*>(PK + (size_t)s * PLANE + e8 * 8 + 4);
        k[0]+=a.x; k[1]+=a.y; k[2]+=a.z; k[3]+=a.w; k[4]+=b.x; k[5]+=b.y; k[6]+=b.z; k[7]+=b.w;
        u16x8 c = PV8[e8 + (size_t)s * stride8];
        #pragma unroll
        for (int i = 0; i < 8; ++i) v[i] += h2f(c[i]);
    }
    u16x8 hi, lo, vb;
    #pragma unroll
    for (int i = 0; i < 8; ++i){
        unsigned short h = f2bf(k[i]);
        hi[i] = h;
        lo[i] = f2bf(k[i] - bf2f(h));
        vb[i] = f2bf(v[i]);
    }
    *reinterpret_cast<u16x8*>(Kp_hi + e8 * 8) = hi;
    *reinterpret_cast<u16x8*>(Kp_lo + e8 * 8) = lo;
    *reinterpret_cast<u16x8*>(Vpt   + e8 * 8) = vb;
}

// ---------------- kernel 3: attention — 512 threads, register-P (R12, proven) ----------------
constexpr int ATTN_LDS_BYTES = (2 * 128 * 72 + 64 * 136) * 2;  // 54,272

__global__ __launch_bounds__(512, 4) void attn_kernel(const float* __restrict__ Q,
                                                      const unsigned short* __restrict__ Kp_hi,
                                                      const unsigned short* __restrict__ Kp_lo,
                                                      const unsigned short* __restrict__ Vpt,
                                                      float* __restrict__ Out){
    extern __shared__ unsigned short smem[];
    unsigned short (*Kh)[72]  = reinterpret_cast<unsigned short (*)[72]>(smem);                 // [128][72]
    unsigned short (*Kl)[72]  = reinterpret_cast<unsigned short (*)[72]>(smem + 128 * 72);      // [128][72]
    unsigned short (*Vt)[136] = reinterpret_cast<unsigned short (*)[136]>(smem + 2 * 128 * 72); // [64][136]

    int bid  = blockIdx.x;
    int orig = (bid & 7) * 128 + (bid >> 3);  // XCD-chunked: 8 heads per XCD
    int bh   = orig >> 4;
    int q0   = (orig & 15) * 256;
    int t = threadIdx.x;              // 0..511
    int w = t >> 6, l = t & 63, l15 = l & 15, lg = l >> 4;

    const float* Qw = Q   + ((size_t)bh * SEQ + q0 + w * 32) * DIM;
    float*       Ow = Out + ((size_t)bh * SEQ + q0 + w * 32) * DIM;

    bf16x8 qh[2][2], ql[2][2];
    #pragma unroll
    for (int rt = 0; rt < 2; ++rt){
        const float* Qb = Qw + (size_t)(rt * 16 + l15) * DIM;
        #pragma unroll
        for (int nk = 0; nk < 2; ++nk){
            float4 a = *reinterpret_cast<const float4*>(Qb + nk * 32 + lg * 8);
            float4 b = *reinterpret_cast<const float4*>(Qb + nk * 32 + lg * 8 + 4);
            float vals[8] = {a.x, a.y, a.z, a.w, b.x, b.y, b.z, b.w};
            #pragma unroll
            for (int i = 0; i < 8; ++i){
                float v = vals[i] * 0.125f;   // fold 1/sqrt(D)
                unsigned short h = f2bf(v);
                qh[rt][nk][i] = (short)h;
                ql[rt][nk][i] = (short)f2bf(v - bf2f(h));
            }
        }
    }

    const unsigned short* KHb = Kp_hi + (size_t)bh * PM * DIM;
    const unsigned short* KLb = Kp_lo + (size_t)bh * PM * DIM;
    const unsigned short* VTb = Vpt   + (size_t)bh * DIM * PM;

    float mx[2], sm[2];
    f32x4 oacc[2][4];   // [rt][dt]
    #pragma unroll
    for (int rt = 0; rt < 2; ++rt){
        mx[rt] = -3.0e38f; sm[rt] = 0.0f;
        #pragma unroll
        for (int dt = 0; dt < 4; ++dt) oacc[rt][dt] = (f32x4)0.0f;
    }

    int srcA = l15 + (lg & 1) * 32;   // P-shuffle source lanes
    int srcB = srcA + 16;
    bool hi2 = (lg & 2) != 0;

    for (int h = 0; h < 2; ++h){
        if (h) __syncthreads();   // all waves done with previous half
        #pragma unroll
        for (int i = 0; i < 2; ++i){
            int idx = i * 512 + t;
            int r = idx >> 3, c = (idx & 7) * 8;
            *reinterpret_cast<u16x8*>(&Kh[r][c]) = *reinterpret_cast<const u16x8*>(KHb + (size_t)(h * 128 + r) * DIM + c);
            *reinterpret_cast<u16x8*>(&Kl[r][c]) = *reinterpret_cast<const u16x8*>(KLb + (size_t)(h * 128 + r) * DIM + c);
        }
        #pragma unroll
        for (int i = 0; i < 2; ++i){
            int idx = i * 512 + t;
            int r = idx >> 4, c = (idx & 15) * 8;
            *reinterpret_cast<u16x8*>(&Vt[r][c]) = *reinterpret_cast<const u16x8*>(VTb + (size_t)r * PM + h * 128 + c);
        }
        __syncthreads();

#define RT_BODY(RT, QT)                                                              \
        {                                                                            \
            f32x4 sa[4];                                                             \
            _Pragma("unroll")                                                        \
            for (int i = 0; i < 4; ++i) sa[i] = (f32x4)0.0f;                         \
            _Pragma("unroll")                                                        \
            for (int mi = 0; mi < 4; ++mi){                                          \
                _Pragma("unroll")                                                    \
                for (int nk = 0; nk < 2; ++nk){                                      \
                    bf16x8 kh_ = *reinterpret_cast<const bf16x8*>(&Kh[QT * 64 + mi * 16 + l15][nk * 32 + lg * 8]); \
                    bf16x8 kl_ = *reinterpret_cast<const bf16x8*>(&Kl[QT * 64 + mi * 16 + l15][nk * 32 + lg * 8]); \
                    sa[mi] = __builtin_amdgcn_mfma_f32_16x16x32_bf16(kh_, qh[RT][nk], sa[mi], 0, 0, 0);  \
                    sa[mi] = __builtin_amdgcn_mfma_f32_16x16x32_bf16(kl_, qh[RT][nk], sa[mi], 0, 0, 0);  \
                    sa[mi] = __builtin_amdgcn_mfma_f32_16x16x32_bf16(kh_, ql[RT][nk], sa[mi], 0, 0, 0);  \
                }                                                                    \
            }                                                                        \
            float hm = -3.0e38f;                                                     \
            _Pragma("unroll")                                                        \
            for (int mi = 0; mi < 4; ++mi)                                           \
                _Pragma("unroll")                                                    \
                for (int j = 0; j < 4; ++j) hm = fmaxf(hm, sa[mi][j]);               \
            hm = fmaxf(hm, __shfl_xor(hm, 16, 64));                                  \
            hm = fmaxf(hm, __shfl_xor(hm, 32, 64));                                  \
            bool keep = __all(hm <= mx[RT] + 8.0f);                                  \
            float nm = keep ? mx[RT] : fmaxf(mx[RT], hm);                            \
            float ps = 0.0f;                                                         \
            _Pragma("unroll")                                                        \
            for (int mi = 0; mi < 4; ++mi)                                           \
                _Pragma("unroll")                                                    \
                for (int j = 0; j < 4; ++j){                                         \
                    float p = __expf(sa[mi][j] - nm);                                \
                    sa[mi][j] = p;                                                   \
                    ps += p;                                                         \
                }                                                                    \
            ps += __shfl_xor(ps, 16, 64);                                            \
            ps += __shfl_xor(ps, 32, 64);                                            \
            if (keep){                                                               \
                sm[RT] += ps;                                                        \
            } else {                                                                 \
                float sc = __expf(mx[RT] - nm);                                      \
                mx[RT] = nm;                                                         \
                sm[RT] = sm[RT] * sc + ps;                                           \
                float scj[4];                                                        \
                _Pragma("unroll")                                                    \
                for (int j = 0; j < 4; ++j) scj[j] = __shfl(sc, lg * 20 + j, 64);    \
                _Pragma("unroll")                                                    \
                for (int dt = 0; dt < 4; ++dt)                                       \
                    _Pragma("unroll")                                                \
                    for (int j = 0; j < 4; ++j) oacc[RT][dt][j] *= scj[j];           \
            }                                                                        \
            int pka[4], pkb[4];                                                      \
            _Pragma("unroll")                                                        \
            for (int mi = 0; mi < 4; ++mi){                                          \
                pka[mi] = (int)(((unsigned)f2bf(sa[mi][0])) | (((unsigned)f2bf(sa[mi][1])) << 16)); \
                pkb[mi] = (int)(((unsigned)f2bf(sa[mi][2])) | (((unsigned)f2bf(sa[mi][3])) << 16)); \
            }                                                                        \
            _Pragma("unroll")                                                        \
            for (int mk = 0; mk < 2; ++mk){                                          \
                int a0 = __shfl(pka[2 * mk],     srcA, 64);                          \
                int a1 = __shfl(pka[2 * mk + 1], srcA, 64);                          \
                int b0 = __shfl(pkb[2 * mk],     srcA, 64);                          \
                int b1 = __shfl(pkb[2 * mk + 1], srcA, 64);                          \
                int c0 = __shfl(pka[2 * mk],     srcB, 64);                          \
                int c1 = __shfl(pka[2 * mk + 1], srcB, 64);                          \
                int e0 = __shfl(pkb[2 * mk],     srcB, 64);                          \
                int e1 = __shfl(pkb[2 * mk + 1], srcB, 64);                          \
                u32x4 pd;                                                            \
                pd.x = (unsigned)(hi2 ? a1 : a0);                                    \
                pd.y = (unsigned)(hi2 ? b1 : b0);                                    \
                pd.z = (unsigned)(hi2 ? c1 : c0);                                    \
                pd.w = (unsigned)(hi2 ? e1 : e0);                                    \
                bf16x8 pa = __builtin_bit_cast(bf16x8, pd);                          \
                _Pragma("unroll")                                                    \
                for (int dt = 0; dt < 4; ++dt){                                      \
                    bf16x8 bv = *reinterpret_cast<const bf16x8*>(&Vt[dt * 16 + l15][QT * 64 + mk * 32 + lg * 8]); \
                    oacc[RT][dt] = __builtin_amdgcn_mfma_f32_16x16x32_bf16(pa, bv, oacc[RT][dt], 0, 0, 0); \
                }                                                                    \
            }                                                                        \
        }

        RT_BODY(0, 0)
        RT_BODY(1, 0)
        RT_BODY(0, 1)
        RT_BODY(1, 1)
#undef RT_BODY
    }

    #pragma unroll
    for (int rt = 0; rt < 2; ++rt){
        float inv = 1.0f / sm[rt];
        float invj[4];
        #pragma unroll
        for (int j = 0; j < 4; ++j) invj[j] = __shfl(inv, lg * 20 + j, 64);
        #pragma unroll
        for (int dt = 0; dt < 4; ++dt)
            #pragma unroll
            for (int j = 0; j < 4; ++j)
                Ow[(size_t)(rt * 16 + lg * 4 + j) * DIM + dt * 16 + l15] = oacc[rt][dt][j] * invj[j];
    }
}

extern "C" void kernel_launch(void* const* d_in, const int* in_sizes, int n_in,
                              void* d_out, int out_size, void* d_ws, size_t ws_size,
                              hipStream_t stream){
    const float* Q = (const float*)d_in[0];
    const float* K = (const float*)d_in[1];
    const float* V = (const float*)d_in[2];
    const float* E = (const float*)d_in[3];
    float* out = (float*)d_out;

    unsigned short* Et_hi = (unsigned short*)d_ws;                       // [M][N]
    unsigned short* Et_lo = Et_hi + (size_t)PM * SEQ;                    // [M][N]
    unsigned short* Kp_hi = Et_lo + (size_t)PM * SEQ;                    // [BH][M][D]
    unsigned short* Kp_lo = Kp_hi + PLANE;                               // [BH][M][D]
    unsigned short* Vpt   = Kp_lo + PLANE;                               // [BH][D][M]
    size_t base_bytes = ((size_t)PM * SEQ * 2 + PLANE * 3) * sizeof(unsigned short);
    float* PK          = reinterpret_cast<float*>((char*)d_ws + base_bytes);  // [8][BH][M][D] f32
    unsigned short* PV = reinterpret_cast<unsigned short*>(PK + 8 * PLANE);   // [8][BH][D][M] f16

    prep_e_kernel<<<256, 256, 0, stream>>>(E, Et_hi, Et_lo);
    proj_partial_kernel<<<1024, 256, 0, stream>>>(K, V, Et_hi, Et_lo, PK, PV);
    reduce_kernel<<<PLANE / 8 / 256, 256, 0, stream>>>(PK, PV, Kp_hi, Kp_lo, Vpt);
    attn_kernel<<<1024, 512, ATTN_LDS_BYTES, stream>>>(Q, Kp_hi, Kp_lo, Vpt, out);
}

// Round 16
// 152.705 us; speedup vs baseline: 1.2363x; 1.0681x over previous
//
#include <hip/hip_runtime.h>

typedef __attribute__((ext_vector_type(8))) short bf16x8;
typedef __attribute__((ext_vector_type(8))) unsigned short u16x8;
typedef __attribute__((ext_vector_type(4))) float f32x4;
typedef __attribute__((ext_vector_type(4))) unsigned int u32x4;

constexpr int BH  = 64;    // B*H
constexpr int SEQ = 4096;  // N
constexpr int DIM = 64;    // D
constexpr int PM  = 256;   // M (proj_len)
constexpr size_t PLANE = (size_t)BH * PM * DIM;   // 1,048,576 elements

__device__ __forceinline__ unsigned short f2bf(float f){
    unsigned int u = __float_as_uint(f);
    return (unsigned short)((u + 0x7fffu + ((u >> 16) & 1u)) >> 16);
}
__device__ __forceinline__ float bf2f(unsigned short h){
    return __uint_as_float(((unsigned int)h) << 16);
}
__device__ __forceinline__ unsigned short f2h(float f){
    _Float16 h = (_Float16)f;
    unsigned short u;
    __builtin_memcpy(&u, &h, 2);
    return u;
}
__device__ __forceinline__ float h2f(unsigned short u){
    _Float16 h;
    __builtin_memcpy(&h, &u, 2);
    return (float)h;
}

// ---------------- kernel 1: E [N][M] f32 -> Et_hi/Et_lo [M][N] bf16 (split) ----------------
__global__ __launch_bounds__(256) void prep_e_kernel(const float* __restrict__ E,
                                                     unsigned short* __restrict__ Et_hi,
                                                     unsigned short* __restrict__ Et_lo){
    __shared__ float T[64][65];
    int n0 = (blockIdx.x & 63) * 64;
    int m0 = (blockIdx.x >> 6) * 64;
    int t = threadIdx.x;
    #pragma unroll
    for (int i = 0; i < 16; ++i){
        int idx = t + i * 256;
        int nl = idx >> 6, ml = idx & 63;
        T[nl][ml] = E[(size_t)(n0 + nl) * PM + (m0 + ml)];
    }
    __syncthreads();
    #pragma unroll
    for (int i = 0; i < 16; ++i){
        int idx = t + i * 256;
        int ml = idx >> 6, nl = idx & 63;
        float v = T[nl][ml];
        unsigned short h = f2bf(v);
        unsigned short lo = f2bf(v - bf2f(h));
        size_t o = (size_t)(m0 + ml) * SEQ + (n0 + nl);
        Et_hi[o] = h;
        Et_lo[o] = lo;
    }
}

// ---------------- kernel 2: projection partials (EXACT R12 config — measured best) ----------
// grid 1024 = 8 s x (64 bh x 2 mh); 256 threads; (256,4) = 4 blocks/CU, 16 waves/CU.
// Register file is EXACTLY full here: acc 64 (AGPR half) + staging/Et 64 (VGPR half).
// R13 (merge mh), R14 (prefetch @4w) both spilled; R15 (prefetch @3w) didn't spill
// but lost more to -25% occupancy than latency hiding gained. Do not add registers.
__global__ __launch_bounds__(256, 4) void proj_partial_kernel(const float* __restrict__ K,
                                                              const float* __restrict__ V,
                                                              const unsigned short* __restrict__ Et_hi,
                                                              const unsigned short* __restrict__ Et_lo,
                                                              float* __restrict__ PK,
                                                              unsigned short* __restrict__ PV){
    __shared__ unsigned short Kh[64][72], Kl[64][72], Vh[64][72];
    int bid   = blockIdx.x;
    int s     = bid & 7;
    int rest  = bid >> 3;          // 0..127
    int mh    = rest & 1;          // m-half: pair-adjacent in dispatch order
    int bh    = rest >> 1;
    int nbase = s * (SEQ / 8);
    int t = threadIdx.x;
    int w = t >> 6, l = t & 63, l15 = l & 15, lg = l >> 4;
    int m0w = mh * 128 + w * 32;   // wave's 32-row m-chunk

    const float* Kb = K + (size_t)bh * SEQ * DIM;
    const float* Vb = V + (size_t)bh * SEQ * DIM;
    int d  = t & 63;
    int ng = t >> 6;               // 0..3

    f32x4 accK[2][4], accV[4][2];  // [ms][dt] / [dt][ms]
    #pragma unroll
    for (int i = 0; i < 2; ++i)
        #pragma unroll
        for (int j = 0; j < 4; ++j){ accK[i][j] = (f32x4)0.0f; accV[j][i] = (f32x4)0.0f; }

    for (int n0 = nbase; n0 < nbase + SEQ / 8; n0 += 64){
        #pragma unroll
        for (int p = 0; p < 2; ++p){
            int nb = p * 32 + ng * 8;
            float kf[8], vf[8];
            #pragma unroll
            for (int i = 0; i < 8; ++i){
                kf[i] = Kb[(size_t)(n0 + nb + i) * DIM + d];
                vf[i] = Vb[(size_t)(n0 + nb + i) * DIM + d];
            }
            u16x8 kh, kl, vh;
            #pragma unroll
            for (int i = 0; i < 8; ++i){
                unsigned short h = f2bf(kf[i]);
                kh[i] = h;
                kl[i] = f2bf(kf[i] - bf2f(h));
                vh[i] = f2bf(vf[i]);
            }
            *reinterpret_cast<u16x8*>(&Kh[d][nb]) = kh;
            *reinterpret_cast<u16x8*>(&Kl[d][nb]) = kl;
            *reinterpret_cast<u16x8*>(&Vh[d][nb]) = vh;
        }
        __syncthreads();
        // Et fragments (L2-resident; loaded after barrier so staging VGPRs are dead)
        bf16x8 eh[2][2], el[2][2];
        #pragma unroll
        for (int nk = 0; nk < 2; ++nk){
            #pragma unroll
            for (int ms = 0; ms < 2; ++ms){
                size_t off = (size_t)(m0w + ms * 16 + l15) * SEQ + (n0 + nk * 32 + lg * 8);
                eh[nk][ms] = *reinterpret_cast<const bf16x8*>(Et_hi + off);
                el[nk][ms] = *reinterpret_cast<const bf16x8*>(Et_lo + off);
            }
        }
        #pragma unroll
        for (int nk = 0; nk < 2; ++nk){
            int kb = nk * 32 + lg * 8;
            #pragma unroll
            for (int dt = 0; dt < 4; ++dt){
                bf16x8 kh = *reinterpret_cast<const bf16x8*>(&Kh[dt * 16 + l15][kb]);
                bf16x8 kl = *reinterpret_cast<const bf16x8*>(&Kl[dt * 16 + l15][kb]);
                bf16x8 vh = *reinterpret_cast<const bf16x8*>(&Vh[dt * 16 + l15][kb]);
                #pragma unroll
                for (int ms = 0; ms < 2; ++ms){
                    accK[ms][dt] = __builtin_amdgcn_mfma_f32_16x16x32_bf16(eh[nk][ms], kh, accK[ms][dt], 0, 0, 0);
                    accK[ms][dt] = __builtin_amdgcn_mfma_f32_16x16x32_bf16(eh[nk][ms], kl, accK[ms][dt], 0, 0, 0);
                    accK[ms][dt] = __builtin_amdgcn_mfma_f32_16x16x32_bf16(el[nk][ms], kh, accK[ms][dt], 0, 0, 0);
                    accV[dt][ms] = __builtin_amdgcn_mfma_f32_16x16x32_bf16(vh, eh[nk][ms], accV[dt][ms], 0, 0, 0);
                }
            }
        }
        __syncthreads();
    }

    float*          PKb = PK + ((size_t)s * BH + bh) * PM * DIM;
    unsigned short* PVb = PV + ((size_t)s * BH + bh) * DIM * PM;
    #pragma unroll
    for (int ms = 0; ms < 2; ++ms){
        #pragma unroll
        for (int dt = 0; dt < 4; ++dt){
            #pragma unroll
            for (int j = 0; j < 4; ++j){
                int mg = m0w + ms * 16 + lg * 4 + j;
                int dg = dt * 16 + l15;
                PKb[(size_t)mg * DIM + dg] = accK[ms][dt][j];
                int dr = dt * 16 + lg * 4 + j;
                int mc = m0w + ms * 16 + l15;
                PVb[(size_t)dr * PM + mc] = f2h(accV[dt][ms][j]);
            }
        }
    }
}

// ---------------- kernel 2b: reduce 8 partials (K f32, V f16) -> Kp_hi/Kp_lo/Vpt ----------------
__global__ __launch_bounds__(256) void reduce_kernel(const float* __restrict__ PK,
                                                     const unsigned short* __restrict__ PV,
                                                     unsigned short* __restrict__ Kp_hi,
                                                     unsigned short* __restrict__ Kp_lo,
                                                     unsigned short* __restrict__ Vpt){
    size_t e8 = (size_t)blockIdx.x * 256 + threadIdx.x;   // 8 elements per thread
    const u16x8* PV8 = reinterpret_cast<const u16x8*>(PV);
    size_t stride8 = PLANE / 8;

    float k[8], v[8];
    {
        float4 a = *reinterpret_cast<const float4*>(PK + e8 * 8);
        float4 b = *reinterpret_cast<const float4*>(PK + e8 * 8 + 4);
        k[0]=a.x; k[1]=a.y; k[2]=a.z; k[3]=a.w; k[4]=b.x; k[5]=b.y; k[6]=b.z; k[7]=b.w;
        u16x8 c = PV8[e8];
        #pragma unroll
        for (int i = 0; i < 8; ++i) v[i] = h2f(c[i]);
    }
    #pragma unroll
    for (int s = 1; s < 8; ++s){
        float4 a = *reinterpret_cast<const float4*>(PK + (size_t)s * PLANE + e8 * 8);
        float4 b = *reinterpret_cast<const float4*>(PK + (size_t)s * PLANE + e8 * 8 + 4);
        k[0]+=a.x; k[1]+=a.y; k[2]+=a.z; k[3]+=a.w; k[4]+=b.x; k[5]+=b.y; k[6]+=b.z; k[7]+=b.w;
        u16x8 c = PV8[e8 + (size_t)s * stride8];
        #pragma unroll
        for (int i = 0; i < 8; ++i) v[i] += h2f(c[i]);
    }
    u16x8 hi, lo, vb;
    #pragma unroll
    for (int i = 0; i < 8; ++i){
        unsigned short h = f2bf(k[i]);
        hi[i] = h;
        lo[i] = f2bf(k[i] - bf2f(h));
        vb[i] = f2bf(v[i]);
    }
    *reinterpret_cast<u16x8*>(Kp_hi + e8 * 8) = hi;
    *reinterpret_cast<u16x8*>(Kp_lo + e8 * 8) = lo;
    *reinterpret_cast<u16x8*>(Vpt   + e8 * 8) = vb;
}

// ---------------- kernel 3: attention — R12 register-P + T5 setprio around MFMA ----------
// grid 1024 = (bh x 16 q-chunks of 256), 512 threads = 8 waves; wave owns 32 q-rows.
// Between staging barriers the 8 waves run desynced phases (QK^T MFMA / softmax
// VALU / PV MFMA) -> T5 role-diversity: setprio(1) around the MFMA clusters
// keeps the matrix pipe fed while other waves do VALU/shuffles (m191: +4-7%).
constexpr int ATTN_LDS_BYTES = (2 * 128 * 72 + 64 * 136) * 2;  // 54,272

__global__ __launch_bounds__(512, 4) void attn_kernel(const float* __restrict__ Q,
                                                      const unsigned short* __restrict__ Kp_hi,
                                                      const unsigned short* __restrict__ Kp_lo,
                                                      const unsigned short* __restrict__ Vpt,
                                                      float* __restrict__ Out){
    extern __shared__ unsigned short smem[];
    unsigned short (*Kh)[72]  = reinterpret_cast<unsigned short (*)[72]>(smem);                 // [128][72]
    unsigned short (*Kl)[72]  = reinterpret_cast<unsigned short (*)[72]>(smem + 128 * 72);      // [128][72]
    unsigned short (*Vt)[136] = reinterpret_cast<unsigned short (*)[136]>(smem + 2 * 128 * 72); // [64][136]

    int bid  = blockIdx.x;
    int orig = (bid & 7) * 128 + (bid >> 3);  // XCD-chunked: 8 heads per XCD
    int bh   = orig >> 4;
    int q0   = (orig & 15) * 256;
    int t = threadIdx.x;              // 0..511
    int w = t >> 6, l = t & 63, l15 = l & 15, lg = l >> 4;

    const float* Qw = Q   + ((size_t)bh * SEQ + q0 + w * 32) * DIM;
    float*       Ow = Out + ((size_t)bh * SEQ + q0 + w * 32) * DIM;

    bf16x8 qh[2][2], ql[2][2];
    #pragma unroll
    for (int rt = 0; rt < 2; ++rt){
        const float* Qb = Qw + (size_t)(rt * 16 + l15) * DIM;
        #pragma unroll
        for (int nk = 0; nk < 2; ++nk){
            float4 a = *reinterpret_cast<const float4*>(Qb + nk * 32 + lg * 8);
            float4 b = *reinterpret_cast<const float4*>(Qb + nk * 32 + lg * 8 + 4);
            float vals[8] = {a.x, a.y, a.z, a.w, b.x, b.y, b.z, b.w};
            #pragma unroll
            for (int i = 0; i < 8; ++i){
                float v = vals[i] * 0.125f;   // fold 1/sqrt(D)
                unsigned short h = f2bf(v);
                qh[rt][nk][i] = (short)h;
                ql[rt][nk][i] = (short)f2bf(v - bf2f(h));
            }
        }
    }

    const unsigned short* KHb = Kp_hi + (size_t)bh * PM * DIM;
    const unsigned short* KLb = Kp_lo + (size_t)bh * PM * DIM;
    const unsigned short* VTb = Vpt   + (size_t)bh * DIM * PM;

    float mx[2], sm[2];
    f32x4 oacc[2][4];   // [rt][dt]
    #pragma unroll
    for (int rt = 0; rt < 2; ++rt){
        mx[rt] = -3.0e38f; sm[rt] = 0.0f;
        #pragma unroll
        for (int dt = 0; dt < 4; ++dt) oacc[rt][dt] = (f32x4)0.0f;
    }

    int srcA = l15 + (lg & 1) * 32;   // P-shuffle source lanes
    int srcB = srcA + 16;
    bool hi2 = (lg & 2) != 0;

    for (int h = 0; h < 2; ++h){
        if (h) __syncthreads();   // all waves done with previous half
        #pragma unroll
        for (int i = 0; i < 2; ++i){
            int idx = i * 512 + t;
            int r = idx >> 3, c = (idx & 7) * 8;
            *reinterpret_cast<u16x8*>(&Kh[r][c]) = *reinterpret_cast<const u16x8*>(KHb + (size_t)(h * 128 + r) * DIM + c);
            *reinterpret_cast<u16x8*>(&Kl[r][c]) = *reinterpret_cast<const u16x8*>(KLb + (size_t)(h * 128 + r) * DIM + c);
        }
        #pragma unroll
        for (int i = 0; i < 2; ++i){
            int idx = i * 512 + t;
            int r = idx >> 4, c = (idx & 15) * 8;
            *reinterpret_cast<u16x8*>(&Vt[r][c]) = *reinterpret_cast<const u16x8*>(VTb + (size_t)r * PM + h * 128 + c);
        }
        __syncthreads();

#define RT_BODY(RT, QT)                                                              \
        {                                                                            \
            f32x4 sa[4];                                                             \
            _Pragma("unroll")                                                        \
            for (int i = 0; i < 4; ++i) sa[i] = (f32x4)0.0f;                         \
            __builtin_amdgcn_s_setprio(1);                                           \
            _Pragma("unroll")                                                        \
            for (int mi = 0; mi < 4; ++mi){                                          \
                _Pragma("unroll")                                                    \
                for (int nk = 0; nk < 2; ++nk){                                      \
                    bf16x8 kh_ = *reinterpret_cast<const bf16x8*>(&Kh[QT * 64 + mi * 16 + l15][nk * 32 + lg * 8]); \
                    bf16x8 kl_ = *reinterpret_cast<const bf16x8*>(&Kl[QT * 64 + mi * 16 + l15][nk * 32 + lg * 8]); \
                    sa[mi] = __builtin_amdgcn_mfma_f32_16x16x32_bf16(kh_, qh[RT][nk], sa[mi], 0, 0, 0);  \
                    sa[mi] = __builtin_amdgcn_mfma_f32_16x16x32_bf16(kl_, qh[RT][nk], sa[mi], 0, 0, 0);  \
                    sa[mi] = __builtin_amdgcn_mfma_f32_16x16x32_bf16(kh_, ql[RT][nk], sa[mi], 0, 0, 0);  \
                }                                                                    \
            }                                                                        \
            __builtin_amdgcn_s_setprio(0);                                           \
            float hm = -3.0e38f;                                                     \
            _Pragma("unroll")                                                        \
            for (int mi = 0; mi < 4; ++mi)                                           \
                _Pragma("unroll")                                                    \
                for (int j = 0; j < 4; ++j) hm = fmaxf(hm, sa[mi][j]);               \
            hm = fmaxf(hm, __shfl_xor(hm, 16, 64));                                  \
            hm = fmaxf(hm, __shfl_xor(hm, 32, 64));                                  \
            bool keep = __all(hm <= mx[RT] + 8.0f);                                  \
            float nm = keep ? mx[RT] : fmaxf(mx[RT], hm);                            \
            float ps = 0.0f;                                                         \
            _Pragma("unroll")                                                        \
            for (int mi = 0; mi < 4; ++mi)                                           \
                _Pragma("unroll")                                                    \
                for (int j = 0; j < 4; ++j){                                         \
                    float p = __expf(sa[mi][j] - nm);                                \
                    sa[mi][j] = p;                                                   \
                    ps += p;                                                         \
                }                                                                    \
            ps += __shfl_xor(ps, 16, 64);                                            \
            ps += __shfl_xor(ps, 32, 64);                                            \
            if (keep){                                                               \
                sm[RT] += ps;                                                        \
            } else {                                                                 \
                float sc = __expf(mx[RT] - nm);                                      \
                mx[RT] = nm;                                                         \
                sm[RT] = sm[RT] * sc + ps;                                           \
                float scj[4];                                                        \
                _Pragma("unroll")                                                    \
                for (int j = 0; j < 4; ++j) scj[j] = __shfl(sc, lg * 20 + j, 64);    \
                _Pragma("unroll")                                                    \
                for (int dt = 0; dt < 4; ++dt)                                       \
                    _Pragma("unroll")                                                \
                    for (int j = 0; j < 4; ++j) oacc[RT][dt][j] *= scj[j];           \
            }                                                                        \
            int pka[4], pkb[4];                                                      \
            _Pragma("unroll")                                                        \
            for (int mi = 0; mi < 4; ++mi){                                          \
                pka[mi] = (int)(((unsigned)f2bf(sa[mi][0])) | (((unsigned)f2bf(sa[mi][1])) << 16)); \
                pkb[mi] = (int)(((unsigned)f2bf(sa[mi][2])) | (((unsigned)f2bf(sa[mi][3])) << 16)); \
            }                                                                        \
            _Pragma("unroll")                                                        \
            for (int mk = 0; mk < 2; ++mk){                                          \
                int a0 = __shfl(pka[2 * mk],     srcA, 64);                          \
                int a1 = __shfl(pka[2 * mk + 1], srcA, 64);                          \
                int b0 = __shfl(pkb[2 * mk],     srcA, 64);                          \
                int b1 = __shfl(pkb[2 * mk + 1], srcA, 64);                          \
                int c0 = __shfl(pka[2 * mk],     srcB, 64);                          \
                int c1 = __shfl(pka[2 * mk + 1], srcB, 64);                          \
                int e0 = __shfl(pkb[2 * mk],     srcB, 64);                          \
                int e1 = __shfl(pkb[2 * mk + 1], srcB, 64);                          \
                u32x4 pd;                                                            \
                pd.x = (unsigned)(hi2 ? a1 : a0);                                    \
                pd.y = (unsigned)(hi2 ? b1 : b0);                                    \
                pd.z = (unsigned)(hi2 ? c1 : c0);                                    \
                pd.w = (unsigned)(hi2 ? e1 : e0);                                    \
                bf16x8 pa = __builtin_bit_cast(bf16x8, pd);                          \
                __builtin_amdgcn_s_setprio(1);                                       \
                _Pragma("unroll")                                                    \
                for (int dt = 0; dt < 4; ++dt){                                      \
                    bf16x8 bv = *reinterpret_cast<const bf16x8*>(&Vt[dt * 16 + l15][QT * 64 + mk * 32 + lg * 8]); \
                    oacc[RT][dt] = __builtin_amdgcn_mfma_f32_16x16x32_bf16(pa, bv, oacc[RT][dt], 0, 0, 0); \
                }                                                                    \
                __builtin_amdgcn_s_setprio(0);                                       \
            }                                                                        \
        }

        RT_BODY(0, 0)
        RT_BODY(1, 0)
        RT_BODY(0, 1)
        RT_BODY(1, 1)
#undef RT_BODY
    }

    #pragma unroll
    for (int rt = 0; rt < 2; ++rt){
        float inv = 1.0f / sm[rt];
        float invj[4];
        #pragma unroll
        for (int j = 0; j < 4; ++j) invj[j] = __shfl(inv, lg * 20 + j, 64);
        #pragma unroll
        for (int dt = 0; dt < 4; ++dt)
            #pragma unroll
            for (int j = 0; j < 4; ++j)
                Ow[(size_t)(rt * 16 + lg * 4 + j) * DIM + dt * 16 + l15] = oacc[rt][dt][j] * invj[j];
    }
}

extern "C" void kernel_launch(void* const* d_in, const int* in_sizes, int n_in,
                              void* d_out, int out_size, void* d_ws, size_t ws_size,
                              hipStream_t stream){
    const float* Q = (const float*)d_in[0];
    const float* K = (const float*)d_in[1];
    const float* V = (const float*)d_in[2];
    const float* E = (const float*)d_in[3];
    float* out = (float*)d_out;

    unsigned short* Et_hi = (unsigned short*)d_ws;                       // [M][N]
    unsigned short* Et_lo = Et_hi + (size_t)PM * SEQ;                    // [M][N]
    unsigned short* Kp_hi = Et_lo + (size_t)PM * SEQ;                    // [BH][M][D]
    unsigned short* Kp_lo = Kp_hi + PLANE;                               // [BH][M][D]
    unsigned short* Vpt   = Kp_lo + PLANE;                               // [BH][D][M]
    size_t base_bytes = ((size_t)PM * SEQ * 2 + PLANE * 3) * sizeof(unsigned short);
    float* PK          = reinterpret_cast<float*>((char*)d_ws + base_bytes);  // [8][BH][M][D] f32
    unsigned short* PV = reinterpret_cast<unsigned short*>(PK + 8 * PLANE);   // [8][BH][D][M] f16

    prep_e_kernel<<<256, 256, 0, stream>>>(E, Et_hi, Et_lo);
    proj_partial_kernel<<<1024, 256, 0, stream>>>(K, V, Et_hi, Et_lo, PK, PV);
    reduce_kernel<<<PLANE / 8 / 256, 256, 0, stream>>>(PK, PV, Kp_hi, Kp_lo, Vpt);
    attn_kernel<<<1024, 512, ATTN_LDS_BYTES, stream>>>(Q, Kp_hi, Kp_lo, Vpt, out);
}

// Round 17
// 148.631 us; speedup vs baseline: 1.2702x; 1.0274x over previous
//
#include <hip/hip_runtime.h>

typedef __attribute__((ext_vector_type(8))) short bf16x8;
typedef __attribute__((ext_vector_type(8))) unsigned short u16x8;
typedef __attribute__((ext_vector_type(4))) float f32x4;
typedef __attribute__((ext_vector_type(4))) unsigned int u32x4;

constexpr int BH  = 64;    // B*H
constexpr int SEQ = 4096;  // N
constexpr int DIM = 64;    // D
constexpr int PM  = 256;   // M (proj_len)
constexpr size_t PLANE = (size_t)BH * PM * DIM;   // 1,048,576 elements

__device__ __forceinline__ unsigned short f2bf(float f){
    unsigned int u = __float_as_uint(f);
    return (unsigned short)((u + 0x7fffu + ((u >> 16) & 1u)) >> 16);
}
__device__ __forceinline__ float bf2f(unsigned short h){
    return __uint_as_float(((unsigned int)h) << 16);
}
__device__ __forceinline__ unsigned short f2h(float f){
    _Float16 h = (_Float16)f;
    unsigned short u;
    __builtin_memcpy(&u, &h, 2);
    return u;
}
__device__ __forceinline__ float h2f(unsigned short u){
    _Float16 h;
    __builtin_memcpy(&h, &u, 2);
    return (float)h;
}

// ---------------- kernel 1: E [N][M] f32 -> Et_hi/Et_lo [M][N] bf16 (split) ----------------
__global__ __launch_bounds__(256) void prep_e_kernel(const float* __restrict__ E,
                                                     unsigned short* __restrict__ Et_hi,
                                                     unsigned short* __restrict__ Et_lo){
    __shared__ float T[64][65];
    int n0 = (blockIdx.x & 63) * 64;
    int m0 = (blockIdx.x >> 6) * 64;
    int t = threadIdx.x;
    #pragma unroll
    for (int i = 0; i < 16; ++i){
        int idx = t + i * 256;
        int nl = idx >> 6, ml = idx & 63;
        T[nl][ml] = E[(size_t)(n0 + nl) * PM + (m0 + ml)];
    }
    __syncthreads();
    #pragma unroll
    for (int i = 0; i < 16; ++i){
        int idx = t + i * 256;
        int ml = idx >> 6, nl = idx & 63;
        float v = T[nl][ml];
        unsigned short h = f2bf(v);
        unsigned short lo = f2bf(v - bf2f(h));
        size_t o = (size_t)(m0 + ml) * SEQ + (n0 + nl);
        Et_hi[o] = h;
        Et_lo[o] = lo;
    }
}

// ---------------- kernel 2: projection partials — R12 config + STAGGERED n-loop ----------
// grid 1024 = 8 s x (64 bh x 2 mh); 256 threads; (256,4) = 4 blocks/CU, 16 waves/CU.
// Register file exactly full (acc 64 AGPR + staging/Et 64 VGPR) — do not add regs.
// NEW: co-resident blocks rotate their (order-independent) n-tile sequence by
// rot = (bid>>3)&3 so neighbors sit 2 iters apart: one block's MFMA phase
// overlaps another's staging phase (breaks the 4-block phase lockstep that
// kept MfmaUtil == VALUBusy == 16%).
__global__ __launch_bounds__(256, 4) void proj_partial_kernel(const float* __restrict__ K,
                                                              const float* __restrict__ V,
                                                              const unsigned short* __restrict__ Et_hi,
                                                              const unsigned short* __restrict__ Et_lo,
                                                              float* __restrict__ PK,
                                                              unsigned short* __restrict__ PV){
    __shared__ unsigned short Kh[64][72], Kl[64][72], Vh[64][72];
    int bid   = blockIdx.x;
    int s     = bid & 7;
    int rest  = bid >> 3;          // 0..127
    int mh    = rest & 1;          // m-half: pair-adjacent in dispatch order
    int bh    = rest >> 1;
    int nbase = s * (SEQ / 8);
    int rot   = rest & 3;          // stagger: mh-pair and bh-neighbor desync by 2 iters
    int t = threadIdx.x;
    int w = t >> 6, l = t & 63, l15 = l & 15, lg = l >> 4;
    int m0w = mh * 128 + w * 32;   // wave's 32-row m-chunk

    const float* Kb = K + (size_t)bh * SEQ * DIM;
    const float* Vb = V + (size_t)bh * SEQ * DIM;
    int d  = t & 63;
    int ng = t >> 6;               // 0..3

    f32x4 accK[2][4], accV[4][2];  // [ms][dt] / [dt][ms]
    #pragma unroll
    for (int i = 0; i < 2; ++i)
        #pragma unroll
        for (int j = 0; j < 4; ++j){ accK[i][j] = (f32x4)0.0f; accV[j][i] = (f32x4)0.0f; }

    for (int it = 0; it < 8; ++it){
        int n0 = nbase + (((it + rot * 2) & 7) << 6);   // rotated tile order (sum order only)
        #pragma unroll
        for (int p = 0; p < 2; ++p){
            int nb = p * 32 + ng * 8;
            float kf[8], vf[8];
            #pragma unroll
            for (int i = 0; i < 8; ++i){
                kf[i] = Kb[(size_t)(n0 + nb + i) * DIM + d];
                vf[i] = Vb[(size_t)(n0 + nb + i) * DIM + d];
            }
            u16x8 kh, kl, vh;
            #pragma unroll
            for (int i = 0; i < 8; ++i){
                unsigned short h = f2bf(kf[i]);
                kh[i] = h;
                kl[i] = f2bf(kf[i] - bf2f(h));
                vh[i] = f2bf(vf[i]);
            }
            *reinterpret_cast<u16x8*>(&Kh[d][nb]) = kh;
            *reinterpret_cast<u16x8*>(&Kl[d][nb]) = kl;
            *reinterpret_cast<u16x8*>(&Vh[d][nb]) = vh;
        }
        __syncthreads();
        // Et fragments (L2-resident; loaded after barrier so staging VGPRs are dead)
        bf16x8 eh[2][2], el[2][2];
        #pragma unroll
        for (int nk = 0; nk < 2; ++nk){
            #pragma unroll
            for (int ms = 0; ms < 2; ++ms){
                size_t off = (size_t)(m0w + ms * 16 + l15) * SEQ + (n0 + nk * 32 + lg * 8);
                eh[nk][ms] = *reinterpret_cast<const bf16x8*>(Et_hi + off);
                el[nk][ms] = *reinterpret_cast<const bf16x8*>(Et_lo + off);
            }
        }
        #pragma unroll
        for (int nk = 0; nk < 2; ++nk){
            int kb = nk * 32 + lg * 8;
            #pragma unroll
            for (int dt = 0; dt < 4; ++dt){
                bf16x8 kh = *reinterpret_cast<const bf16x8*>(&Kh[dt * 16 + l15][kb]);
                bf16x8 kl = *reinterpret_cast<const bf16x8*>(&Kl[dt * 16 + l15][kb]);
                bf16x8 vh = *reinterpret_cast<const bf16x8*>(&Vh[dt * 16 + l15][kb]);
                #pragma unroll
                for (int ms = 0; ms < 2; ++ms){
                    accK[ms][dt] = __builtin_amdgcn_mfma_f32_16x16x32_bf16(eh[nk][ms], kh, accK[ms][dt], 0, 0, 0);
                    accK[ms][dt] = __builtin_amdgcn_mfma_f32_16x16x32_bf16(eh[nk][ms], kl, accK[ms][dt], 0, 0, 0);
                    accK[ms][dt] = __builtin_amdgcn_mfma_f32_16x16x32_bf16(el[nk][ms], kh, accK[ms][dt], 0, 0, 0);
                    accV[dt][ms] = __builtin_amdgcn_mfma_f32_16x16x32_bf16(vh, eh[nk][ms], accV[dt][ms], 0, 0, 0);
                }
            }
        }
        __syncthreads();
    }

    float*          PKb = PK + ((size_t)s * BH + bh) * PM * DIM;
    unsigned short* PVb = PV + ((size_t)s * BH + bh) * DIM * PM;
    #pragma unroll
    for (int ms = 0; ms < 2; ++ms){
        #pragma unroll
        for (int dt = 0; dt < 4; ++dt){
            #pragma unroll
            for (int j = 0; j < 4; ++j){
                int mg = m0w + ms * 16 + lg * 4 + j;
                int dg = dt * 16 + l15;
                PKb[(size_t)mg * DIM + dg] = accK[ms][dt][j];
                int dr = dt * 16 + lg * 4 + j;
                int mc = m0w + ms * 16 + l15;
                PVb[(size_t)dr * PM + mc] = f2h(accV[dt][ms][j]);
            }
        }
    }
}

// ---------------- kernel 2b: reduce 8 partials (K f32, V f16) -> Kp_hi/Kp_lo/Vpt ----------------
__global__ __launch_bounds__(256) void reduce_kernel(const float* __restrict__ PK,
                                                     const unsigned short* __restrict__ PV,
                                                     unsigned short* __restrict__ Kp_hi,
                                                     unsigned short* __restrict__ Kp_lo,
                                                     unsigned short* __restrict__ Vpt){
    size_t e8 = (size_t)blockIdx.x * 256 + threadIdx.x;   // 8 elements per thread
    const u16x8* PV8 = reinterpret_cast<const u16x8*>(PV);
    size_t stride8 = PLANE / 8;

    float k[8], v[8];
    {
        float4 a = *reinterpret_cast<const float4*>(PK + e8 * 8);
        float4 b = *reinterpret_cast<const float4*>(PK + e8 * 8 + 4);
        k[0]=a.x; k[1]=a.y; k[2]=a.z; k[3]=a.w; k[4]=b.x; k[5]=b.y; k[6]=b.z; k[7]=b.w;
        u16x8 c = PV8[e8];
        #pragma unroll
        for (int i = 0; i < 8; ++i) v[i] = h2f(c[i]);
    }
    #pragma unroll
    for (int s = 1; s < 8; ++s){
        float4 a = *reinterpret_cast<const float4*>(PK + (size_t)s * PLANE + e8 * 8);
        float4 b = *reinterpret_cast<const float4*>(PK + (size_t)s * PLANE + e8 * 8 + 4);
        k[0]+=a.x; k[1]+=a.y; k[2]+=a.z; k[3]+=a.w; k[4]+=b.x; k[5]+=b.y; k[6]+=b.z; k[7]+=b.w;
        u16x8 c = PV8[e8 + (size_t)s * stride8];
        #pragma unroll
        for (int i = 0; i < 8; ++i) v[i] += h2f(c[i]);
    }
    u16x8 hi, lo, vb;
    #pragma unroll
    for (int i = 0; i < 8; ++i){
        unsigned short h = f2bf(k[i]);
        hi[i] = h;
        lo[i] = f2bf(k[i] - bf2f(h));
        vb[i] = f2bf(v[i]);
    }
    *reinterpret_cast<u16x8*>(Kp_hi + e8 * 8) = hi;
    *reinterpret_cast<u16x8*>(Kp_lo + e8 * 8) = lo;
    *reinterpret_cast<u16x8*>(Vpt   + e8 * 8) = vb;
}

// ---------------- kernel 3: attention — R12 register-P (+ setprio, neutral) ----------------
constexpr int ATTN_LDS_BYTES = (2 * 128 * 72 + 64 * 136) * 2;  // 54,272

__global__ __launch_bounds__(512, 4) void attn_kernel(const float* __restrict__ Q,
                                                      const unsigned short* __restrict__ Kp_hi,
                                                      const unsigned short* __restrict__ Kp_lo,
                                                      const unsigned short* __restrict__ Vpt,
                                                      float* __restrict__ Out){
    extern __shared__ unsigned short smem[];
    unsigned short (*Kh)[72]  = reinterpret_cast<unsigned short (*)[72]>(smem);                 // [128][72]
    unsigned short (*Kl)[72]  = reinterpret_cast<unsigned short (*)[72]>(smem + 128 * 72);      // [128][72]
    unsigned short (*Vt)[136] = reinterpret_cast<unsigned short (*)[136]>(smem + 2 * 128 * 72); // [64][136]

    int bid  = blockIdx.x;
    int orig = (bid & 7) * 128 + (bid >> 3);  // XCD-chunked: 8 heads per XCD
    int bh   = orig >> 4;
    int q0   = (orig & 15) * 256;
    int t = threadIdx.x;              // 0..511
    int w = t >> 6, l = t & 63, l15 = l & 15, lg = l >> 4;

    const float* Qw = Q   + ((size_t)bh * SEQ + q0 + w * 32) * DIM;
    float*       Ow = Out + ((size_t)bh * SEQ + q0 + w * 32) * DIM;

    bf16x8 qh[2][2], ql[2][2];
    #pragma unroll
    for (int rt = 0; rt < 2; ++rt){
        const float* Qb = Qw + (size_t)(rt * 16 + l15) * DIM;
        #pragma unroll
        for (int nk = 0; nk < 2; ++nk){
            float4 a = *reinterpret_cast<const float4*>(Qb + nk * 32 + lg * 8);
            float4 b = *reinterpret_cast<const float4*>(Qb + nk * 32 + lg * 8 + 4);
            float vals[8] = {a.x, a.y, a.z, a.w, b.x, b.y, b.z, b.w};
            #pragma unroll
            for (int i = 0; i < 8; ++i){
                float v = vals[i] * 0.125f;   // fold 1/sqrt(D)
                unsigned short h = f2bf(v);
                qh[rt][nk][i] = (short)h;
                ql[rt][nk][i] = (short)f2bf(v - bf2f(h));
            }
        }
    }

    const unsigned short* KHb = Kp_hi + (size_t)bh * PM * DIM;
    const unsigned short* KLb = Kp_lo + (size_t)bh * PM * DIM;
    const unsigned short* VTb = Vpt   + (size_t)bh * DIM * PM;

    float mx[2], sm[2];
    f32x4 oacc[2][4];   // [rt][dt]
    #pragma unroll
    for (int rt = 0; rt < 2; ++rt){
        mx[rt] = -3.0e38f; sm[rt] = 0.0f;
        #pragma unroll
        for (int dt = 0; dt < 4; ++dt) oacc[rt][dt] = (f32x4)0.0f;
    }

    int srcA = l15 + (lg & 1) * 32;   // P-shuffle source lanes
    int srcB = srcA + 16;
    bool hi2 = (lg & 2) != 0;

    for (int h = 0; h < 2; ++h){
        if (h) __syncthreads();   // all waves done with previous half
        #pragma unroll
        for (int i = 0; i < 2; ++i){
            int idx = i * 512 + t;
            int r = idx >> 3, c = (idx & 7) * 8;
            *reinterpret_cast<u16x8*>(&Kh[r][c]) = *reinterpret_cast<const u16x8*>(KHb + (size_t)(h * 128 + r) * DIM + c);
            *reinterpret_cast<u16x8*>(&Kl[r][c]) = *reinterpret_cast<const u16x8*>(KLb + (size_t)(h * 128 + r) * DIM + c);
        }
        #pragma unroll
        for (int i = 0; i < 2; ++i){
            int idx = i * 512 + t;
            int r = idx >> 4, c = (idx & 15) * 8;
            *reinterpret_cast<u16x8*>(&Vt[r][c]) = *reinterpret_cast<const u16x8*>(VTb + (size_t)r * PM + h * 128 + c);
        }
        __syncthreads();

#define RT_BODY(RT, QT)                                                              \
        {                                                                            \
            f32x4 sa[4];                                                             \
            _Pragma("unroll")                                                        \
            for (int i = 0; i < 4; ++i) sa[i] = (f32x4)0.0f;                         \
            __builtin_amdgcn_s_setprio(1);                                           \
            _Pragma("unroll")                                                        \
            for (int mi = 0; mi < 4; ++mi){                                          \
                _Pragma("unroll")                                                    \
                for (int nk = 0; nk < 2; ++nk){                                      \
                    bf16x8 kh_ = *reinterpret_cast<const bf16x8*>(&Kh[QT * 64 + mi * 16 + l15][nk * 32 + lg * 8]); \
                    bf16x8 kl_ = *reinterpret_cast<const bf16x8*>(&Kl[QT * 64 + mi * 16 + l15][nk * 32 + lg * 8]); \
                    sa[mi] = __builtin_amdgcn_mfma_f32_16x16x32_bf16(kh_, qh[RT][nk], sa[mi], 0, 0, 0);  \
                    sa[mi] = __builtin_amdgcn_mfma_f32_16x16x32_bf16(kl_, qh[RT][nk], sa[mi], 0, 0, 0);  \
                    sa[mi] = __builtin_amdgcn_mfma_f32_16x16x32_bf16(kh_, ql[RT][nk], sa[mi], 0, 0, 0);  \
                }                                                                    \
            }                                                                        \
            __builtin_amdgcn_s_setprio(0);                                           \
            float hm = -3.0e38f;                                                     \
            _Pragma("unroll")                                                        \
            for (int mi = 0; mi < 4; ++mi)                                           \
                _Pragma("unroll")                                                    \
                for (int j = 0; j < 4; ++j) hm = fmaxf(hm, sa[mi][j]);               \
            hm = fmaxf(hm, __shfl_xor(hm, 16, 64));                                  \
            hm = fmaxf(hm, __shfl_xor(hm, 32, 64));                                  \
            bool keep = __all(hm <= mx[RT] + 8.0f);                                  \
            float nm = keep ? mx[RT] : fmaxf(mx[RT], hm);                            \
            float ps = 0.0f;                                                         \
            _Pragma("unroll")                                                        \
            for (int mi = 0; mi < 4; ++mi)                                           \
                _Pragma("unroll")                                                    \
                for (int j = 0; j < 4; ++j){                                         \
                    float p = __expf(sa[mi][j] - nm);                                \
                    sa[mi][j] = p;                                                   \
                    ps += p;                                                         \
                }                                                                    \
            ps += __shfl_xor(ps, 16, 64);                                            \
            ps += __shfl_xor(ps, 32, 64);                                            \
            if (keep){                                                               \
                sm[RT] += ps;                                                        \
            } else {                                                                 \
                float sc = __expf(mx[RT] - nm);                                      \
                mx[RT] = nm;                                                         \
                sm[RT] = sm[RT] * sc + ps;                                           \
                float scj[4];                                                        \
                _Pragma("unroll")                                                    \
                for (int j = 0; j < 4; ++j) scj[j] = __shfl(sc, lg * 20 + j, 64);    \
                _Pragma("unroll")                                                    \
                for (int dt = 0; dt < 4; ++dt)                                       \
                    _Pragma("unroll")                                                \
                    for (int j = 0; j < 4; ++j) oacc[RT][dt][j] *= scj[j];           \
            }                                                                        \
            int pka[4], pkb[4];                                                      \
            _Pragma("unroll")                                                        \
            for (int mi = 0; mi < 4; ++mi){                                          \
                pka[mi] = (int)(((unsigned)f2bf(sa[mi][0])) | (((unsigned)f2bf(sa[mi][1])) << 16)); \
                pkb[mi] = (int)(((unsigned)f2bf(sa[mi][2])) | (((unsigned)f2bf(sa[mi][3])) << 16)); \
            }                                                                        \
            _Pragma("unroll")                                                        \
            for (int mk = 0; mk < 2; ++mk){                                          \
                int a0 = __shfl(pka[2 * mk],     srcA, 64);                          \
                int a1 = __shfl(pka[2 * mk + 1], srcA, 64);                          \
                int b0 = __shfl(pkb[2 * mk],     srcA, 64);                          \
                int b1 = __shfl(pkb[2 * mk + 1], srcA, 64);                          \
                int c0 = __shfl(pka[2 * mk],     srcB, 64);                          \
                int c1 = __shfl(pka[2 * mk + 1], srcB, 64);                          \
                int e0 = __shfl(pkb[2 * mk],     srcB, 64);                          \
                int e1 = __shfl(pkb[2 * mk + 1], srcB, 64);                          \
                u32x4 pd;                                                            \
                pd.x = (unsigned)(hi2 ? a1 : a0);                                    \
                pd.y = (unsigned)(hi2 ? b1 : b0);                                    \
                pd.z = (unsigned)(hi2 ? c1 : c0);                                    \
                pd.w = (unsigned)(hi2 ? e1 : e0);                                    \
                bf16x8 pa = __builtin_bit_cast(bf16x8, pd);                          \
                __builtin_amdgcn_s_setprio(1);                                       \
                _Pragma("unroll")                                                    \
                for (int dt = 0; dt < 4; ++dt){                                      \
                    bf16x8 bv = *reinterpret_cast<const bf16x8*>(&Vt[dt * 16 + l15][QT * 64 + mk * 32 + lg * 8]); \
                    oacc[RT][dt] = __builtin_amdgcn_mfma_f32_16x16x32_bf16(pa, bv, oacc[RT][dt], 0, 0, 0); \
                }                                                                    \
                __builtin_amdgcn_s_setprio(0);                                       \
            }                                                                        \
        }

        RT_BODY(0, 0)
        RT_BODY(1, 0)
        RT_BODY(0, 1)
        RT_BODY(1, 1)
#undef RT_BODY
    }

    #pragma unroll
    for (int rt = 0; rt < 2; ++rt){
        float inv = 1.0f / sm[rt];
        float invj[4];
        #pragma unroll
        for (int j = 0; j < 4; ++j) invj[j] = __shfl(inv, lg * 20 + j, 64);
        #pragma unroll
        for (int dt = 0; dt < 4; ++dt)
            #pragma unroll
            for (int j = 0; j < 4; ++j)
                Ow[(size_t)(rt * 16 + lg * 4 + j) * DIM + dt * 16 + l15] = oacc[rt][dt][j] * invj[j];
    }
}

extern "C" void kernel_launch(void* const* d_in, const int* in_sizes, int n_in,
                              void* d_out, int out_size, void* d_ws, size_t ws_size,
                              hipStream_t stream){
    const float* Q = (const float*)d_in[0];
    const float* K = (const float*)d_in[1];
    const float* V = (const float*)d_in[2];
    const float* E = (const float*)d_in[3];
    float* out = (float*)d_out;

    unsigned short* Et_hi = (unsigned short*)d_ws;                       // [M][N]
    unsigned short* Et_lo = Et_hi + (size_t)PM * SEQ;                    // [M][N]
    unsigned short* Kp_hi = Et_lo + (size_t)PM * SEQ;                    // [BH][M][D]
    unsigned short* Kp_lo = Kp_hi + PLANE;                               // [BH][M][D]
    unsigned short* Vpt   = Kp_lo + PLANE;                               // [BH][D][M]
    size_t base_bytes = ((size_t)PM * SEQ * 2 + PLANE * 3) * sizeof(unsigned short);
    float* PK          = reinterpret_cast<float*>((char*)d_ws + base_bytes);  // [8][BH][M][D] f32
    unsigned short* PV = reinterpret_cast<unsigned short*>(PK + 8 * PLANE);   // [8][BH][D][M] f16

    prep_e_kernel<<<256, 256, 0, stream>>>(E, Et_hi, Et_lo);
    proj_partial_kernel<<<1024, 256, 0, stream>>>(K, V, Et_hi, Et_lo, PK, PV);
    reduce_kernel<<<PLANE / 8 / 256, 256, 0, stream>>>(PK, PV, Kp_hi, Kp_lo, Vpt);
    attn_kernel<<<1024, 512, ATTN_LDS_BYTES, stream>>>(Q, Kp_hi, Kp_lo, Vpt, out);
}